// Round 10
// baseline (458.780 us; speedup 1.0000x reference)
//
#include <hip/hip_runtime.h>

#define NN 100000
#define EE 1600000
#define GG 1000
#define PERG 100
#define KK 30
#define HH 64

#define NB 782      // buckets of 128 nodes: 782*128 = 100096 >= NN
#define CAP 4096    // max edges/bucket (mean 2048, sigma ~45 -> huge margin)
#define CHB 4096    // edges per bucket block -> 391 bucket blocks
#define BUCKET_BLOCKS ((EE + CHB - 1) / CHB)  // 391
#define PROJ64_BLOCKS ((NN + 63) / 64)        // 1563 (BM=64 proj tiles)
#define LAYER_BLOCKS ((NN + 63) / 64)         // 1563 (BM=64 tiles)

typedef _Float16 half4_t __attribute__((ext_vector_type(4)));
typedef _Float16 half8_t __attribute__((ext_vector_type(8)));

// ---- bucket body: LDS histogram + per-(block,bucket) run reservation ----
// needs 3*NB = 2346 ints = 9384 B of the shared 9600 B.
__device__ __forceinline__ void bucket_body(int bid, float* smem,
                                            const int* __restrict__ src,
                                            const int* __restrict__ dst,
                                            int* __restrict__ gcur,
                                            int* __restrict__ pairs) {
  int* lhist = (int*)smem;
  int* lbase = lhist + NB;
  int* lcur = lbase + NB;
  const int t = threadIdx.x;
  const int c0 = bid * CHB;
  const int c1 = min(c0 + CHB, EE);
  for (int b = t; b < NB; b += 256) {
    lhist[b] = 0;
    lcur[b] = 0;
  }
  __syncthreads();
  for (int e = c0 + t; e < c1; e += 256) atomicAdd(&lhist[dst[e] >> 7], 1);
  __syncthreads();
  for (int b = t; b < NB; b += 256) {
    int c = lhist[b];
    lbase[b] = c ? atomicAdd(&gcur[b], c) : 0;
  }
  __syncthreads();
  for (int e = c0 + t; e < c1; e += 256) {
    int d = dst[e];
    int b = d >> 7;
    int p = atomicAdd(&lcur[b], 1);
    pairs[b * CAP + lbase[b] + p] = (src[e] << 7) | (d & 127);
  }
}

// ---- proj body v2: BM=64, W from global (L1 bcast), X staged in BK=32 LDS
// chunks (64*36*4 = 9216 B). Mirrors the verified layer_kernel phase B.
// 8 blocks/CU (wave-slot cap) vs old BM=128's 4 -> barrier stalls hidden.
template <int K>
__device__ __forceinline__ void proj_body(int bid, float* xs,
                                          const float* __restrict__ X,
                                          const float* __restrict__ WL,
                                          const float* __restrict__ WR,
                                          float* __restrict__ P,
                                          float* __restrict__ R) {
  constexpr int XSP = 36;
  const int t = threadIdx.x;
  const int row0 = bid * 64;
  const int tc = t & 15, tr = t >> 4;
  const float* WB = (tc < 8) ? WL : WR;
  const int wcolg = (tc & 7) * 8;

  float acc[4][8];
#pragma unroll
  for (int i = 0; i < 4; ++i)
#pragma unroll
    for (int j = 0; j < 8; ++j) acc[i][j] = 0.f;

  for (int k0 = 0; k0 < K; k0 += 32) {
    __syncthreads();
    // stage X[row0..row0+64) x [k0..k0+32) -> xs (2 iters of 256 threads)
    for (int idx = t; idx < 64 * 8; idx += 256) {
      int r = idx >> 3, c = idx & 7;
      int row = row0 + r;
      float4 v = make_float4(0.f, 0.f, 0.f, 0.f);
      if (row < NN) v = *reinterpret_cast<const float4*>(&X[(size_t)row * K + k0 + c * 4]);
      *reinterpret_cast<float4*>(&xs[r * XSP + c * 4]) = v;
    }
    __syncthreads();
    for (int kk4 = 0; kk4 < 32; kk4 += 4) {
      float4 a[4];
#pragma unroll
      for (int i = 0; i < 4; ++i)
        a[i] = *reinterpret_cast<const float4*>(&xs[(tr + 16 * i) * XSP + kk4]);
#pragma unroll
      for (int kk = 0; kk < 4; ++kk) {
        float4 b0 = *reinterpret_cast<const float4*>(&WB[(size_t)(k0 + kk4 + kk) * 64 + wcolg]);
        float4 b1 = *reinterpret_cast<const float4*>(&WB[(size_t)(k0 + kk4 + kk) * 64 + wcolg + 4]);
        float bv[8] = {b0.x, b0.y, b0.z, b0.w, b1.x, b1.y, b1.z, b1.w};
#pragma unroll
        for (int i = 0; i < 4; ++i) {
          float av = (kk == 0) ? a[i].x : (kk == 1) ? a[i].y : (kk == 2) ? a[i].z : a[i].w;
#pragma unroll
          for (int j = 0; j < 8; ++j) acc[i][j] = fmaf(av, bv[j], acc[i][j]);
        }
      }
    }
  }

  float* OUT = (tc < 8) ? P : R;
  const int cb = (tc & 7) * 8;
#pragma unroll
  for (int i = 0; i < 4; ++i) {
    int row = row0 + tr + 16 * i;
    if (row < NN) {
      *reinterpret_cast<float4*>(&OUT[(size_t)row * 64 + cb]) =
          make_float4(acc[i][0], acc[i][1], acc[i][2], acc[i][3]);
      *reinterpret_cast<float4*>(&OUT[(size_t)row * 64 + cb + 4]) =
          make_float4(acc[i][4], acc[i][5], acc[i][6], acc[i][7]);
    }
  }
}

// Heterogeneous launch: 1563 proj(BM=64) + 391 bucket = 1954 blocks <= 2048
// resident slots at 8 blocks/CU (9600 B LDS, low VGPR) -> whole grid
// co-resident; bucket work fully hidden under proj.
__global__ __launch_bounds__(256) void fused_bucket_proj(const int* __restrict__ src,
                                                         const int* __restrict__ dst,
                                                         int* __restrict__ gcur,
                                                         int* __restrict__ pairs,
                                                         const float* __restrict__ X,
                                                         const float* __restrict__ WL,
                                                         const float* __restrict__ WR,
                                                         float* __restrict__ P,
                                                         float* __restrict__ R) {
  __shared__ float smem[2400];  // 9600 B: proj xs (9216) / bucket hists (9384)
  if (blockIdx.x < PROJ64_BLOCKS)
    proj_body<128>(blockIdx.x, smem, X, WL, WR, P, R);
  else
    bucket_body(blockIdx.x - PROJ64_BLOCKS, smem, src, dst, gcur, pairs);
}

// Phase C with inline scan -> row_start/cnt/eidx (CSR sorted by dst).
__global__ __launch_bounds__(256) void csr_kernel(const int* __restrict__ gcur,
                                                  const int* __restrict__ pairs,
                                                  int* __restrict__ row_start,
                                                  int* __restrict__ cnt,
                                                  int* __restrict__ eidx) {
  __shared__ int vals[CAP];
  __shared__ int hist[128];
  __shared__ int offs[128];
  __shared__ int cur[128];
  __shared__ int red[4];
  const int b = blockIdx.x;
  const int t = threadIdx.x;
  int s = 0;
  for (int i = t; i < b; i += 256) s += gcur[i];
#pragma unroll
  for (int off = 32; off > 0; off >>= 1) s += __shfl_xor(s, off);
  if ((t & 63) == 0) red[t >> 6] = s;
  if (t < 128) {
    hist[t] = 0;
    cur[t] = 0;
  }
  __syncthreads();
  const int base = red[0] + red[1] + red[2] + red[3];
  const int nb = gcur[b];
  for (int i = t; i < nb; i += 256) {
    int v = pairs[b * CAP + i];
    vals[i] = v;
    atomicAdd(&hist[v & 127], 1);
  }
  __syncthreads();
  if (t < 128) {
    int ss = 0;
    for (int m = 0; m < t; ++m) ss += hist[m];
    offs[t] = ss;
    int node = b * 128 + t;
    if (node < NN) {
      row_start[node] = base + ss;
      cnt[node] = hist[t];
    }
  }
  __syncthreads();
  for (int i = t; i < nb; i += 256) {
    int v = vals[i];
    int ld = v & 127;
    int p = atomicAdd(&cur[ld], 1);
    eidx[base + offs[ld] + p] = v >> 7;
  }
}

// ---- fused layer, BM=64: agg_n (fp32 gather into LDS) + proj_{n+1} GEMM ----
// HOUT=false: Pout fp32 (ranking path — fp16 here flipped top-30, r8).
// HOUT=true (layer2): P output as fp16 PoutH for sel_head's post-selection
// gather only; fp32 col-63 keyP/keyR are the exact ranking inputs.
template <bool HOUT>
__global__ __launch_bounds__(256) void layer_kernel(const float* __restrict__ P,
                                                    const float* __restrict__ R,
                                                    const float* __restrict__ bias,
                                                    const int* __restrict__ row_start,
                                                    const int* __restrict__ cnt,
                                                    const int* __restrict__ eidx,
                                                    const float* __restrict__ WL,
                                                    const float* __restrict__ WR,
                                                    float* __restrict__ Pout,
                                                    _Float16* __restrict__ PoutH,
                                                    float* __restrict__ Rout,
                                                    float* __restrict__ keyP,
                                                    float* __restrict__ keyR) {
  __shared__ float hs[64 * 68];  // 17408 B
  const int t = threadIdx.x;
  const int lane = t & 63;
  const int qd = t >> 4;   // quarter id 0..15
  const int ql = t & 15;   // feature quarter
  const int row0 = blockIdx.x * 64;

  // ---- phase A: gather (mean aggr + bias + self + relu) into LDS ----
  for (int p = 0; p < 4; ++p) {
    const int r = qd + 16 * p;
    const int node = row0 + r;
    float4 acc = make_float4(0.f, 0.f, 0.f, 0.f);
    if (node < NN) {
      const int base = row_start[node];
      const int deg = cnt[node];
      for (int e0 = 0; e0 < deg; e0 += 16) {
        const int rem = deg - e0;
        const int ii = (ql < rem) ? ql : (rem - 1);
        int idx = eidx[base + e0 + ii];
#pragma unroll
        for (int j = 0; j < 16; ++j) {
          const int sj = __shfl(idx, (lane & 48) | j);
          const float wj = (j < rem) ? 1.f : 0.f;
          const float4 vj = *reinterpret_cast<const float4*>(&P[(size_t)sj * 64 + ql * 4]);
          acc.x = fmaf(wj, vj.x, acc.x);
          acc.y = fmaf(wj, vj.y, acc.y);
          acc.z = fmaf(wj, vj.z, acc.z);
          acc.w = fmaf(wj, vj.w, acc.w);
        }
      }
      const float dv = fmaxf((float)deg, 1.0f);
      const float4 r4 = *reinterpret_cast<const float4*>(&R[(size_t)node * 64 + ql * 4]);
      const float4 b4 = *reinterpret_cast<const float4*>(&bias[ql * 4]);
      acc.x = fmaxf(acc.x / dv + b4.x + r4.x, 0.f);
      acc.y = fmaxf(acc.y / dv + b4.y + r4.y, 0.f);
      acc.z = fmaxf(acc.z / dv + b4.z + r4.z, 0.f);
      acc.w = fmaxf(acc.w / dv + b4.w + r4.w, 0.f);
    }
    *reinterpret_cast<float4*>(&hs[r * 68 + ql * 4]) = acc;
  }
  __syncthreads();

  // ---- phase B: [64x64] @ [64x128] GEMM, 4x8 reg tile per thread ----
  const int tc = t & 15, tr = t >> 4;
  const float* WB = (tc < 8) ? WL : WR;
  const int wcolg = (tc & 7) * 8;

  float acc[4][8];
#pragma unroll
  for (int i = 0; i < 4; ++i)
#pragma unroll
    for (int j = 0; j < 8; ++j) acc[i][j] = 0.f;

  for (int kk4 = 0; kk4 < 64; kk4 += 4) {
    float4 a[4];
#pragma unroll
    for (int i = 0; i < 4; ++i)
      a[i] = *reinterpret_cast<const float4*>(&hs[(tr + 16 * i) * 68 + kk4]);
#pragma unroll
    for (int kk = 0; kk < 4; ++kk) {
      float4 b0 = *reinterpret_cast<const float4*>(&WB[(kk4 + kk) * 64 + wcolg]);
      float4 b1 = *reinterpret_cast<const float4*>(&WB[(kk4 + kk) * 64 + wcolg + 4]);
      float bv[8] = {b0.x, b0.y, b0.z, b0.w, b1.x, b1.y, b1.z, b1.w};
#pragma unroll
      for (int i = 0; i < 4; ++i) {
        float av = (kk == 0) ? a[i].x : (kk == 1) ? a[i].y : (kk == 2) ? a[i].z : a[i].w;
#pragma unroll
        for (int j = 0; j < 8; ++j) acc[i][j] = fmaf(av, bv[j], acc[i][j]);
      }
    }
  }

  const int cb = (tc & 7) * 8;
  if (tc < 8) {
#pragma unroll
    for (int i = 0; i < 4; ++i) {
      int row = row0 + tr + 16 * i;
      if (row < NN) {
        if (HOUT) {
          half8_t hv;
#pragma unroll
          for (int j = 0; j < 8; ++j) hv[j] = (_Float16)acc[i][j];
          *reinterpret_cast<half8_t*>(&PoutH[(size_t)row * 64 + cb]) = hv;
          if (keyP != nullptr && tc == 7) keyP[row] = acc[i][7];  // col63 fp32
        } else {
          *reinterpret_cast<float4*>(&Pout[(size_t)row * 64 + cb]) =
              make_float4(acc[i][0], acc[i][1], acc[i][2], acc[i][3]);
          *reinterpret_cast<float4*>(&Pout[(size_t)row * 64 + cb + 4]) =
              make_float4(acc[i][4], acc[i][5], acc[i][6], acc[i][7]);
        }
      }
    }
  } else {
#pragma unroll
    for (int i = 0; i < 4; ++i) {
      int row = row0 + tr + 16 * i;
      if (row < NN) {
        *reinterpret_cast<float4*>(&Rout[(size_t)row * 64 + cb]) =
            make_float4(acc[i][0], acc[i][1], acc[i][2], acc[i][3]);
        *reinterpret_cast<float4*>(&Rout[(size_t)row * 64 + cb + 4]) =
            make_float4(acc[i][4], acc[i][5], acc[i][6], acc[i][7]);
        if (HOUT && keyR != nullptr && tc == 15) keyR[row] = acc[i][7];
      }
    }
  }
}

// ---- sel_head: per-graph keys (fp32, exact) + top-30 selection + compact
// layer-3 gather (fp16 table, post-selection -> bounded error) + conv1d + MLP.
__global__ __launch_bounds__(256) void sel_head(const _Float16* __restrict__ Ph,
                                                const float* __restrict__ R,
                                                const float* __restrict__ b3,
                                                const float* __restrict__ keyP,
                                                const float* __restrict__ keyR,
                                                const int* __restrict__ row_start,
                                                const int* __restrict__ cnt,
                                                const int* __restrict__ eidx,
                                                const float* __restrict__ cw,
                                                const float* __restrict__ cb,
                                                const float* __restrict__ w1,
                                                const float* __restrict__ bb1,
                                                const float* __restrict__ w2,
                                                const float* __restrict__ bb2,
                                                float* __restrict__ out) {
  __shared__ float key[PERG];
  __shared__ int sel[32];
  __shared__ float feat[34 * 65];
  __shared__ float cwT[192 * 33];
  __shared__ float z[896];
  __shared__ float psum[256];
  const int g = blockIdx.x;
  const int t = threadIdx.x;

  // conv-weight transpose staging runs concurrently with key computation
  for (int idx = t; idx < 32 * 192; idx += 256) {
    int o = idx / 192, k = idx % 192;
    cwT[k * 33 + o] = cw[idx];
  }
  if (t < PERG) {
    const int node = g * PERG + t;
    const int base = row_start[node];
    const int deg = cnt[node];
    float s = 0.f;
    for (int e = 0; e < deg; ++e) s += keyP[eidx[base + e]];
    key[t] = fmaxf(s / fmaxf((float)deg, 1.f) + b3[63] + keyR[node], 0.f);
  }
  __syncthreads();

  if (t < PERG) {
    float kv = key[t];
    int r = 0;
    for (int m = 0; m < PERG; ++m) {
      float km = key[m];
      r += (int)((km > kv) || (km == kv && m < t));
    }
    if (r < KK) sel[r] = t;
  }
  __syncthreads();

  // compact gather: 30 selected nodes, full 64-feature layer-3 aggregation
  const int lane = t & 63;
  const int qd = t >> 4;   // quarter id 0..15
  const int ql = t & 15;   // feature quarter
  for (int p = 0; p < 2; ++p) {
    const int r = qd + 16 * p;
    if (r < KK) {  // quarter-uniform branch; shfl stays within the quarter
      const int node = g * PERG + sel[r];
      const int base = row_start[node];
      const int deg = cnt[node];
      float4 acc = make_float4(0.f, 0.f, 0.f, 0.f);
      for (int e0 = 0; e0 < deg; e0 += 16) {
        const int rem = deg - e0;
        const int ii = (ql < rem) ? ql : (rem - 1);
        int idx = eidx[base + e0 + ii];
#pragma unroll
        for (int j = 0; j < 16; ++j) {
          const int sj = __shfl(idx, (lane & 48) | j);
          const float wj = (j < rem) ? 1.f : 0.f;
          const half4_t hv =
              *reinterpret_cast<const half4_t*>(&Ph[(size_t)sj * 64 + ql * 4]);
          acc.x = fmaf(wj, (float)hv.x, acc.x);
          acc.y = fmaf(wj, (float)hv.y, acc.y);
          acc.z = fmaf(wj, (float)hv.z, acc.z);
          acc.w = fmaf(wj, (float)hv.w, acc.w);
        }
      }
      const float dv = fmaxf((float)deg, 1.0f);
      const float4 r4 = *reinterpret_cast<const float4*>(&R[(size_t)node * 64 + ql * 4]);
      const float4 b4 = *reinterpret_cast<const float4*>(&b3[ql * 4]);
      feat[r * 65 + ql * 4 + 0] = fmaxf(acc.x / dv + b4.x + r4.x, 0.f);
      feat[r * 65 + ql * 4 + 1] = fmaxf(acc.y / dv + b4.y + r4.y, 0.f);
      feat[r * 65 + ql * 4 + 2] = fmaxf(acc.z / dv + b4.z + r4.z, 0.f);
      feat[r * 65 + ql * 4 + 3] = fmaxf(acc.w / dv + b4.w + r4.w, 0.f);
    }
  }
  __syncthreads();

  {
    const int o = t & 31;
    const int pg = t >> 5;
    float zacc[4] = {0.f, 0.f, 0.f, 0.f};
    int i = 0, tt = 0;
    for (int k = 0; k < 192; ++k) {
      float c = cwT[k * 33 + o];
#pragma unroll
      for (int j = 0; j < 4; ++j) {
        int p = pg + 8 * j;
        zacc[j] = fmaf(c, feat[(p + tt) * 65 + i], zacc[j]);
      }
      if (++tt == 3) {
        tt = 0;
        ++i;
      }
    }
    float cbo = cb[o];
#pragma unroll
    for (int j = 0; j < 4; ++j) {
      int p = pg + 8 * j;
      if (p < 28) z[o * 28 + p] = fmaxf(zacc[j] + cbo, 0.f);
    }
  }
  __syncthreads();

  {
    const int hh = t & 63;
    const int quarter = t >> 6;
    const int q0 = quarter * 224;
    float acc = 0.f;
    for (int q = 0; q < 224; ++q)
      acc = fmaf(z[q0 + q], w1[(size_t)(q0 + q) * 64 + hh], acc);
    psum[t] = acc;
  }
  __syncthreads();

  if (t < 64) {
    float o1 = fmaxf(bb1[t] + psum[t] + psum[t + 64] + psum[t + 128] + psum[t + 192], 0.f);
    float v = o1 * w2[t];
#pragma unroll
    for (int off = 32; off > 0; off >>= 1) v += __shfl_down(v, off);
    if (t == 0) out[g] = v + bb2[0];
  }
}

extern "C" void kernel_launch(void* const* d_in, const int* in_sizes, int n_in,
                              void* d_out, int out_size, void* d_ws, size_t ws_size,
                              hipStream_t stream) {
  const float* x = (const float*)d_in[0];
  const int* src = (const int*)d_in[1];
  const int* dst = (const int*)d_in[2];
  const float* wl1 = (const float*)d_in[4];
  const float* wr1 = (const float*)d_in[5];
  const float* b1 = (const float*)d_in[6];
  const float* wl2 = (const float*)d_in[7];
  const float* wr2 = (const float*)d_in[8];
  const float* b2 = (const float*)d_in[9];
  const float* wl3 = (const float*)d_in[10];
  const float* wr3 = (const float*)d_in[11];
  const float* b3 = (const float*)d_in[12];
  const float* cw = (const float*)d_in[13];
  const float* cb = (const float*)d_in[14];
  const float* w1 = (const float*)d_in[15];
  const float* bb1 = (const float*)d_in[16];
  const float* w2 = (const float*)d_in[17];
  const float* bb2 = (const float*)d_in[18];
  float* out = (float*)d_out;

  char* w = (char*)d_ws;
  auto carve = [&](size_t bytes) {
    char* p = w;
    w += (bytes + 255) & ~(size_t)255;
    return p;
  };
  int* row_start = (int*)carve((size_t)NN * 4);
  int* cnt = (int*)carve((size_t)NN * 4);
  int* eidx = (int*)carve((size_t)EE * 4);
  float* P1 = (float*)carve((size_t)NN * 64 * 4);
  float* R1 = (float*)carve((size_t)NN * 64 * 4);
  float* P2 = (float*)carve((size_t)NN * 64 * 4);
  float* R2 = (float*)carve((size_t)NN * 64 * 4);
  _Float16* PhF = (_Float16*)carve((size_t)NN * 64 * 2);  // final gather table
  float* keyP = (float*)carve((size_t)NN * 4);
  float* keyR = (float*)carve((size_t)NN * 4);
  int* gcur = (int*)carve((size_t)NB * 4);
  // pairs aliases P2: csr consumes pairs before layer1 writes P2.
  int* pairs = (int*)P2;

  hipMemsetAsync(gcur, 0, (size_t)NB * 4, stream);
  fused_bucket_proj<<<BUCKET_BLOCKS + PROJ64_BLOCKS, 256, 0, stream>>>(
      src, dst, gcur, pairs, x, wl1, wr1, P1, R1);
  csr_kernel<<<NB, 256, 0, stream>>>(gcur, pairs, row_start, cnt, eidx);

  // layer1 (fp32 out): agg(P1,R1,b1) -> P2,R2 = h1 @ (wl2|wr2)
  layer_kernel<false><<<LAYER_BLOCKS, 256, 0, stream>>>(
      P1, R1, b1, row_start, cnt, eidx, wl2, wr2, P2, nullptr, R2, nullptr, nullptr);
  // layer2 (fp16 P out + fp32 keys): agg(P2,R2,b2) -> PhF,R1 = h2 @ (wl3|wr3)
  layer_kernel<true><<<LAYER_BLOCKS, 256, 0, stream>>>(
      P2, R2, b2, row_start, cnt, eidx, wl3, wr3, nullptr, PhF, R1, keyP, keyR);
  // keys (fp32 exact) + selection + compact fp16 gather + conv + MLP
  sel_head<<<GG, 256, 0, stream>>>(PhF, R1, b3, keyP, keyR, row_start, cnt, eidx,
                                   cw, cb, w1, bb1, w2, bb2, out);
}

// Round 11
// 442.006 us; speedup vs baseline: 1.0379x; 1.0379x over previous
//
#include <hip/hip_runtime.h>

#define NN 100000
#define EE 1600000
#define GG 1000
#define PERG 100
#define KK 30
#define HH 64

#define NB 782      // buckets of 128 nodes: 782*128 = 100096 >= NN
#define CAP 4096    // max edges/bucket (mean 2048, sigma ~45 -> huge margin)
#define CHB 4096    // edges per bucket block -> 391 bucket blocks
#define BUCKET_BLOCKS ((EE + CHB - 1) / CHB)  // 391
#define PROJ_BLOCKS ((NN + 127) / 128)        // 782 (BM=128 proj tiles)
#define LAYER_BLOCKS ((NN + 63) / 64)         // 1563 (BM=64 layer tiles)

typedef _Float16 half4_t __attribute__((ext_vector_type(4)));
typedef _Float16 half8_t __attribute__((ext_vector_type(8)));

// ---- bucket body: LDS histogram + per-(block,bucket) run reservation ----
__device__ __forceinline__ void bucket_body(int bid, float* smem,
                                            const int* __restrict__ src,
                                            const int* __restrict__ dst,
                                            int* __restrict__ gcur,
                                            int* __restrict__ pairs) {
  int* lhist = (int*)smem;
  int* lbase = lhist + NB;
  int* lcur = lbase + NB;
  const int t = threadIdx.x;
  const int c0 = bid * CHB;
  const int c1 = min(c0 + CHB, EE);
  for (int b = t; b < NB; b += 256) {
    lhist[b] = 0;
    lcur[b] = 0;
  }
  __syncthreads();
  for (int e = c0 + t; e < c1; e += 256) atomicAdd(&lhist[dst[e] >> 7], 1);
  __syncthreads();
  for (int b = t; b < NB; b += 256) {
    int c = lhist[b];
    lbase[b] = c ? atomicAdd(&gcur[b], c) : 0;
  }
  __syncthreads();
  for (int e = c0 + t; e < c1; e += 256) {
    int d = dst[e];
    int b = d >> 7;
    int p = atomicAdd(&lcur[b], 1);
    pairs[b * CAP + lbase[b] + p] = (src[e] << 7) | (d & 127);
  }
}

// ---- proj body (r9 verified): X [NN,K] @ (WL|WR) -> P, R. BM=128 ----
// W staged in LDS per K-chunk; 8x8 acc/thread. r10's BM=64 W-from-global
// variant regressed 88->113us (halved per-barrier work + VMEM inner loop).
template <int K>
__device__ __forceinline__ void proj_body(int bid, float* smem,
                                          const float* __restrict__ X,
                                          const float* __restrict__ WL,
                                          const float* __restrict__ WR,
                                          float* __restrict__ P,
                                          float* __restrict__ R) {
  constexpr int BM = 128, BK = 32, XSP = 36, WSP = 144;
  float* xs = smem;             // 128*36 floats
  float* ws = smem + BM * XSP;  // 32*144 floats
  const int t = threadIdx.x;
  const int row0 = bid * BM;
  const int tc = t & 15, tr = t >> 4;
  const int wcol = tc * 8 + (tc >> 2) * 4;

  float acc[8][8];
#pragma unroll
  for (int i = 0; i < 8; ++i)
#pragma unroll
    for (int j = 0; j < 8; ++j) acc[i][j] = 0.f;

  for (int k0 = 0; k0 < K; k0 += BK) {
    __syncthreads();
    for (int idx = t; idx < BM * 8; idx += 256) {
      int r = idx >> 3, c = idx & 7;
      int row = row0 + r;
      float4 v = make_float4(0.f, 0.f, 0.f, 0.f);
      if (row < NN) v = *reinterpret_cast<const float4*>(&X[(size_t)row * K + k0 + c * 4]);
      *reinterpret_cast<float4*>(&xs[r * XSP + c * 4]) = v;
    }
    for (int idx = t; idx < BK * 16; idx += 256) {
      int kr = idx >> 4, c4 = idx & 15;
      int gcl = c4 >> 1;
      int off = gcl * 8 + (gcl >> 2) * 4 + (c4 & 1) * 4;
      *reinterpret_cast<float4*>(&ws[kr * WSP + off]) =
          *reinterpret_cast<const float4*>(&WL[(k0 + kr) * 64 + c4 * 4]);
      int g2 = gcl + 8;
      int off2 = g2 * 8 + (g2 >> 2) * 4 + (c4 & 1) * 4;
      *reinterpret_cast<float4*>(&ws[kr * WSP + off2]) =
          *reinterpret_cast<const float4*>(&WR[(k0 + kr) * 64 + c4 * 4]);
    }
    __syncthreads();
    for (int kk4 = 0; kk4 < BK; kk4 += 4) {
      float4 a[8];
#pragma unroll
      for (int i = 0; i < 8; ++i)
        a[i] = *reinterpret_cast<const float4*>(&xs[(tr + 16 * i) * XSP + kk4]);
#pragma unroll
      for (int kk = 0; kk < 4; ++kk) {
        float4 b0 = *reinterpret_cast<const float4*>(&ws[(kk4 + kk) * WSP + wcol]);
        float4 b1 = *reinterpret_cast<const float4*>(&ws[(kk4 + kk) * WSP + wcol + 4]);
        float bv[8] = {b0.x, b0.y, b0.z, b0.w, b1.x, b1.y, b1.z, b1.w};
#pragma unroll
        for (int i = 0; i < 8; ++i) {
          float av = (kk == 0) ? a[i].x : (kk == 1) ? a[i].y : (kk == 2) ? a[i].z : a[i].w;
#pragma unroll
          for (int j = 0; j < 8; ++j) acc[i][j] = fmaf(av, bv[j], acc[i][j]);
        }
      }
    }
  }

  float* OUT = (tc < 8) ? P : R;
  int cb = (tc & 7) * 8;
#pragma unroll
  for (int i = 0; i < 8; ++i) {
    int row = row0 + tr + 16 * i;
    if (row < NN) {
      *reinterpret_cast<float4*>(&OUT[(size_t)row * 64 + cb]) =
          make_float4(acc[i][0], acc[i][1], acc[i][2], acc[i][3]);
      *reinterpret_cast<float4*>(&OUT[(size_t)row * 64 + cb + 4]) =
          make_float4(acc[i][4], acc[i][5], acc[i][6], acc[i][7]);
    }
  }
}

// Heterogeneous launch: proj blocks first (all resident), buckets backfill.
__global__ __launch_bounds__(256) void fused_bucket_proj(const int* __restrict__ src,
                                                         const int* __restrict__ dst,
                                                         int* __restrict__ gcur,
                                                         int* __restrict__ pairs,
                                                         const float* __restrict__ X,
                                                         const float* __restrict__ WL,
                                                         const float* __restrict__ WR,
                                                         float* __restrict__ P,
                                                         float* __restrict__ R) {
  __shared__ float smem[128 * 36 + 32 * 144];  // 36864 B, covers both roles
  if (blockIdx.x < PROJ_BLOCKS)
    proj_body<128>(blockIdx.x, smem, X, WL, WR, P, R);
  else
    bucket_body(blockIdx.x - PROJ_BLOCKS, smem, src, dst, gcur, pairs);
}

// Phase C with inline scan -> row_start/cnt/eidx (CSR sorted by dst).
__global__ __launch_bounds__(256) void csr_kernel(const int* __restrict__ gcur,
                                                  const int* __restrict__ pairs,
                                                  int* __restrict__ row_start,
                                                  int* __restrict__ cnt,
                                                  int* __restrict__ eidx) {
  __shared__ int vals[CAP];
  __shared__ int hist[128];
  __shared__ int offs[128];
  __shared__ int cur[128];
  __shared__ int red[4];
  const int b = blockIdx.x;
  const int t = threadIdx.x;
  int s = 0;
  for (int i = t; i < b; i += 256) s += gcur[i];
#pragma unroll
  for (int off = 32; off > 0; off >>= 1) s += __shfl_xor(s, off);
  if ((t & 63) == 0) red[t >> 6] = s;
  if (t < 128) {
    hist[t] = 0;
    cur[t] = 0;
  }
  __syncthreads();
  const int base = red[0] + red[1] + red[2] + red[3];
  const int nb = gcur[b];
  for (int i = t; i < nb; i += 256) {
    int v = pairs[b * CAP + i];
    vals[i] = v;
    atomicAdd(&hist[v & 127], 1);
  }
  __syncthreads();
  if (t < 128) {
    int ss = 0;
    for (int m = 0; m < t; ++m) ss += hist[m];
    offs[t] = ss;
    int node = b * 128 + t;
    if (node < NN) {
      row_start[node] = base + ss;
      cnt[node] = hist[t];
    }
  }
  __syncthreads();
  for (int i = t; i < nb; i += 256) {
    int v = vals[i];
    int ld = v & 127;
    int p = atomicAdd(&cur[ld], 1);
    eidx[base + offs[ld] + p] = v >> 7;
  }
}

// ---- fused layer, BM=64: agg_n (fp32 gather into LDS) + proj_{n+1} GEMM ----
// HOUT=false: Pout fp32 (ranking path — fp16 here flipped top-30, r8).
// HOUT=true (layer2): P output as fp16 PoutH for sel_head's post-selection
// gather only; fp32 col-63 keyP/keyR are the exact ranking inputs.
template <bool HOUT>
__global__ __launch_bounds__(256) void layer_kernel(const float* __restrict__ P,
                                                    const float* __restrict__ R,
                                                    const float* __restrict__ bias,
                                                    const int* __restrict__ row_start,
                                                    const int* __restrict__ cnt,
                                                    const int* __restrict__ eidx,
                                                    const float* __restrict__ WL,
                                                    const float* __restrict__ WR,
                                                    float* __restrict__ Pout,
                                                    _Float16* __restrict__ PoutH,
                                                    float* __restrict__ Rout,
                                                    float* __restrict__ keyP,
                                                    float* __restrict__ keyR) {
  __shared__ float hs[64 * 68];  // 17408 B
  const int t = threadIdx.x;
  const int lane = t & 63;
  const int qd = t >> 4;   // quarter id 0..15
  const int ql = t & 15;   // feature quarter
  const int row0 = blockIdx.x * 64;

  // ---- phase A: gather (mean aggr + bias + self + relu) into LDS ----
  for (int p = 0; p < 4; ++p) {
    const int r = qd + 16 * p;
    const int node = row0 + r;
    float4 acc = make_float4(0.f, 0.f, 0.f, 0.f);
    if (node < NN) {
      const int base = row_start[node];
      const int deg = cnt[node];
      for (int e0 = 0; e0 < deg; e0 += 16) {
        const int rem = deg - e0;
        const int ii = (ql < rem) ? ql : (rem - 1);
        int idx = eidx[base + e0 + ii];
#pragma unroll
        for (int j = 0; j < 16; ++j) {
          const int sj = __shfl(idx, (lane & 48) | j);
          const float wj = (j < rem) ? 1.f : 0.f;
          const float4 vj = *reinterpret_cast<const float4*>(&P[(size_t)sj * 64 + ql * 4]);
          acc.x = fmaf(wj, vj.x, acc.x);
          acc.y = fmaf(wj, vj.y, acc.y);
          acc.z = fmaf(wj, vj.z, acc.z);
          acc.w = fmaf(wj, vj.w, acc.w);
        }
      }
      const float dv = fmaxf((float)deg, 1.0f);
      const float4 r4 = *reinterpret_cast<const float4*>(&R[(size_t)node * 64 + ql * 4]);
      const float4 b4 = *reinterpret_cast<const float4*>(&bias[ql * 4]);
      acc.x = fmaxf(acc.x / dv + b4.x + r4.x, 0.f);
      acc.y = fmaxf(acc.y / dv + b4.y + r4.y, 0.f);
      acc.z = fmaxf(acc.z / dv + b4.z + r4.z, 0.f);
      acc.w = fmaxf(acc.w / dv + b4.w + r4.w, 0.f);
    }
    *reinterpret_cast<float4*>(&hs[r * 68 + ql * 4]) = acc;
  }
  __syncthreads();

  // ---- phase B: [64x64] @ [64x128] GEMM, 4x8 reg tile per thread ----
  const int tc = t & 15, tr = t >> 4;
  const float* WB = (tc < 8) ? WL : WR;
  const int wcolg = (tc & 7) * 8;

  float acc[4][8];
#pragma unroll
  for (int i = 0; i < 4; ++i)
#pragma unroll
    for (int j = 0; j < 8; ++j) acc[i][j] = 0.f;

  for (int kk4 = 0; kk4 < 64; kk4 += 4) {
    float4 a[4];
#pragma unroll
    for (int i = 0; i < 4; ++i)
      a[i] = *reinterpret_cast<const float4*>(&hs[(tr + 16 * i) * 68 + kk4]);
#pragma unroll
    for (int kk = 0; kk < 4; ++kk) {
      float4 b0 = *reinterpret_cast<const float4*>(&WB[(kk4 + kk) * 64 + wcolg]);
      float4 b1 = *reinterpret_cast<const float4*>(&WB[(kk4 + kk) * 64 + wcolg + 4]);
      float bv[8] = {b0.x, b0.y, b0.z, b0.w, b1.x, b1.y, b1.z, b1.w};
#pragma unroll
      for (int i = 0; i < 4; ++i) {
        float av = (kk == 0) ? a[i].x : (kk == 1) ? a[i].y : (kk == 2) ? a[i].z : a[i].w;
#pragma unroll
        for (int j = 0; j < 8; ++j) acc[i][j] = fmaf(av, bv[j], acc[i][j]);
      }
    }
  }

  const int cb = (tc & 7) * 8;
  if (tc < 8) {
#pragma unroll
    for (int i = 0; i < 4; ++i) {
      int row = row0 + tr + 16 * i;
      if (row < NN) {
        if (HOUT) {
          half8_t hv;
#pragma unroll
          for (int j = 0; j < 8; ++j) hv[j] = (_Float16)acc[i][j];
          *reinterpret_cast<half8_t*>(&PoutH[(size_t)row * 64 + cb]) = hv;
          if (keyP != nullptr && tc == 7) keyP[row] = acc[i][7];  // col63 fp32
        } else {
          *reinterpret_cast<float4*>(&Pout[(size_t)row * 64 + cb]) =
              make_float4(acc[i][0], acc[i][1], acc[i][2], acc[i][3]);
          *reinterpret_cast<float4*>(&Pout[(size_t)row * 64 + cb + 4]) =
              make_float4(acc[i][4], acc[i][5], acc[i][6], acc[i][7]);
        }
      }
    }
  } else {
#pragma unroll
    for (int i = 0; i < 4; ++i) {
      int row = row0 + tr + 16 * i;
      if (row < NN) {
        *reinterpret_cast<float4*>(&Rout[(size_t)row * 64 + cb]) =
            make_float4(acc[i][0], acc[i][1], acc[i][2], acc[i][3]);
        *reinterpret_cast<float4*>(&Rout[(size_t)row * 64 + cb + 4]) =
            make_float4(acc[i][4], acc[i][5], acc[i][6], acc[i][7]);
        if (HOUT && keyR != nullptr && tc == 15) keyR[row] = acc[i][7];
      }
    }
  }
}

// ---- sel_head: per-graph keys (fp32, exact values; sum order changed —
// precedented safe) + top-30 selection + compact layer-3 gather (fp16 table,
// post-selection) + conv1d + MLP.
// Key phase v2: 16-lane quarter per node (was: 1 thread per node with a
// serial eidx->keyP dependent chain). Lanes sum edges strided; 4-step
// shfl_xor (1,2,4,8 stay within the quarter) reduces.
__global__ __launch_bounds__(256) void sel_head(const _Float16* __restrict__ Ph,
                                                const float* __restrict__ R,
                                                const float* __restrict__ b3,
                                                const float* __restrict__ keyP,
                                                const float* __restrict__ keyR,
                                                const int* __restrict__ row_start,
                                                const int* __restrict__ cnt,
                                                const int* __restrict__ eidx,
                                                const float* __restrict__ cw,
                                                const float* __restrict__ cb,
                                                const float* __restrict__ w1,
                                                const float* __restrict__ bb1,
                                                const float* __restrict__ w2,
                                                const float* __restrict__ bb2,
                                                float* __restrict__ out) {
  __shared__ float key[PERG];
  __shared__ int sel[32];
  __shared__ float feat[34 * 65];
  __shared__ float cwT[192 * 33];
  __shared__ float z[896];
  __shared__ float psum[256];
  const int g = blockIdx.x;
  const int t = threadIdx.x;
  const int qd = t >> 4;   // quarter id 0..15
  const int ql = t & 15;   // lane within quarter

  // conv-weight transpose staging runs concurrently with key computation
  for (int idx = t; idx < 32 * 192; idx += 256) {
    int o = idx / 192, k = idx % 192;
    cwT[k * 33 + o] = cw[idx];
  }
  // key phase: quarter per node, 7 rounds cover 112 >= 100 nodes
  const float b63 = b3[63];
  for (int p = 0; p < 7; ++p) {
    const int r = qd + 16 * p;
    if (r < PERG) {
      const int node = g * PERG + r;
      const int base = row_start[node];
      const int deg = cnt[node];
      float s = 0.f;
      for (int e = ql; e < deg; e += 16) s += keyP[eidx[base + e]];
#pragma unroll
      for (int off = 1; off < 16; off <<= 1) s += __shfl_xor(s, off);
      if (ql == 0)
        key[r] = fmaxf(s / fmaxf((float)deg, 1.f) + b63 + keyR[node], 0.f);
    }
  }
  __syncthreads();

  if (t < PERG) {
    float kv = key[t];
    int r = 0;
    for (int m = 0; m < PERG; ++m) {
      float km = key[m];
      r += (int)((km > kv) || (km == kv && m < t));
    }
    if (r < KK) sel[r] = t;
  }
  __syncthreads();

  // compact gather: 30 selected nodes, full 64-feature layer-3 aggregation
  const int lane = t & 63;
  for (int p = 0; p < 2; ++p) {
    const int r = qd + 16 * p;
    if (r < KK) {  // quarter-uniform branch; shfl stays within the quarter
      const int node = g * PERG + sel[r];
      const int base = row_start[node];
      const int deg = cnt[node];
      float4 acc = make_float4(0.f, 0.f, 0.f, 0.f);
      for (int e0 = 0; e0 < deg; e0 += 16) {
        const int rem = deg - e0;
        const int ii = (ql < rem) ? ql : (rem - 1);
        int idx = eidx[base + e0 + ii];
#pragma unroll
        for (int j = 0; j < 16; ++j) {
          const int sj = __shfl(idx, (lane & 48) | j);
          const float wj = (j < rem) ? 1.f : 0.f;
          const half4_t hv =
              *reinterpret_cast<const half4_t*>(&Ph[(size_t)sj * 64 + ql * 4]);
          acc.x = fmaf(wj, (float)hv.x, acc.x);
          acc.y = fmaf(wj, (float)hv.y, acc.y);
          acc.z = fmaf(wj, (float)hv.z, acc.z);
          acc.w = fmaf(wj, (float)hv.w, acc.w);
        }
      }
      const float dv = fmaxf((float)deg, 1.0f);
      const float4 r4 = *reinterpret_cast<const float4*>(&R[(size_t)node * 64 + ql * 4]);
      const float4 b4 = *reinterpret_cast<const float4*>(&b3[ql * 4]);
      feat[r * 65 + ql * 4 + 0] = fmaxf(acc.x / dv + b4.x + r4.x, 0.f);
      feat[r * 65 + ql * 4 + 1] = fmaxf(acc.y / dv + b4.y + r4.y, 0.f);
      feat[r * 65 + ql * 4 + 2] = fmaxf(acc.z / dv + b4.z + r4.z, 0.f);
      feat[r * 65 + ql * 4 + 3] = fmaxf(acc.w / dv + b4.w + r4.w, 0.f);
    }
  }
  __syncthreads();

  {
    const int o = t & 31;
    const int pg = t >> 5;
    float zacc[4] = {0.f, 0.f, 0.f, 0.f};
    int i = 0, tt = 0;
    for (int k = 0; k < 192; ++k) {
      float c = cwT[k * 33 + o];
#pragma unroll
      for (int j = 0; j < 4; ++j) {
        int p = pg + 8 * j;
        zacc[j] = fmaf(c, feat[(p + tt) * 65 + i], zacc[j]);
      }
      if (++tt == 3) {
        tt = 0;
        ++i;
      }
    }
    float cbo = cb[o];
#pragma unroll
    for (int j = 0; j < 4; ++j) {
      int p = pg + 8 * j;
      if (p < 28) z[o * 28 + p] = fmaxf(zacc[j] + cbo, 0.f);
    }
  }
  __syncthreads();

  {
    const int hh = t & 63;
    const int quarter = t >> 6;
    const int q0 = quarter * 224;
    float acc = 0.f;
    for (int q = 0; q < 224; ++q)
      acc = fmaf(z[q0 + q], w1[(size_t)(q0 + q) * 64 + hh], acc);
    psum[t] = acc;
  }
  __syncthreads();

  if (t < 64) {
    float o1 = fmaxf(bb1[t] + psum[t] + psum[t + 64] + psum[t + 128] + psum[t + 192], 0.f);
    float v = o1 * w2[t];
#pragma unroll
    for (int off = 32; off > 0; off >>= 1) v += __shfl_down(v, off);
    if (t == 0) out[g] = v + bb2[0];
  }
}

extern "C" void kernel_launch(void* const* d_in, const int* in_sizes, int n_in,
                              void* d_out, int out_size, void* d_ws, size_t ws_size,
                              hipStream_t stream) {
  const float* x = (const float*)d_in[0];
  const int* src = (const int*)d_in[1];
  const int* dst = (const int*)d_in[2];
  const float* wl1 = (const float*)d_in[4];
  const float* wr1 = (const float*)d_in[5];
  const float* b1 = (const float*)d_in[6];
  const float* wl2 = (const float*)d_in[7];
  const float* wr2 = (const float*)d_in[8];
  const float* b2 = (const float*)d_in[9];
  const float* wl3 = (const float*)d_in[10];
  const float* wr3 = (const float*)d_in[11];
  const float* b3 = (const float*)d_in[12];
  const float* cw = (const float*)d_in[13];
  const float* cb = (const float*)d_in[14];
  const float* w1 = (const float*)d_in[15];
  const float* bb1 = (const float*)d_in[16];
  const float* w2 = (const float*)d_in[17];
  const float* bb2 = (const float*)d_in[18];
  float* out = (float*)d_out;

  char* w = (char*)d_ws;
  auto carve = [&](size_t bytes) {
    char* p = w;
    w += (bytes + 255) & ~(size_t)255;
    return p;
  };
  int* row_start = (int*)carve((size_t)NN * 4);
  int* cnt = (int*)carve((size_t)NN * 4);
  int* eidx = (int*)carve((size_t)EE * 4);
  float* P1 = (float*)carve((size_t)NN * 64 * 4);
  float* R1 = (float*)carve((size_t)NN * 64 * 4);
  float* P2 = (float*)carve((size_t)NN * 64 * 4);
  float* R2 = (float*)carve((size_t)NN * 64 * 4);
  _Float16* PhF = (_Float16*)carve((size_t)NN * 64 * 2);  // final gather table
  float* keyP = (float*)carve((size_t)NN * 4);
  float* keyR = (float*)carve((size_t)NN * 4);
  int* gcur = (int*)carve((size_t)NB * 4);
  // pairs aliases P2: csr consumes pairs before layer1 writes P2.
  int* pairs = (int*)P2;

  hipMemsetAsync(gcur, 0, (size_t)NB * 4, stream);
  fused_bucket_proj<<<BUCKET_BLOCKS + PROJ_BLOCKS, 256, 0, stream>>>(
      src, dst, gcur, pairs, x, wl1, wr1, P1, R1);
  csr_kernel<<<NB, 256, 0, stream>>>(gcur, pairs, row_start, cnt, eidx);

  // layer1 (fp32 out): agg(P1,R1,b1) -> P2,R2 = h1 @ (wl2|wr2)
  layer_kernel<false><<<LAYER_BLOCKS, 256, 0, stream>>>(
      P1, R1, b1, row_start, cnt, eidx, wl2, wr2, P2, nullptr, R2, nullptr, nullptr);
  // layer2 (fp16 P out + fp32 keys): agg(P2,R2,b2) -> PhF,R1 = h2 @ (wl3|wr3)
  layer_kernel<true><<<LAYER_BLOCKS, 256, 0, stream>>>(
      P2, R2, b2, row_start, cnt, eidx, wl3, wr3, nullptr, PhF, R1, keyP, keyR);
  // keys (fp32 exact) + selection + compact fp16 gather + conv + MLP
  sel_head<<<GG, 256, 0, stream>>>(PhF, R1, b3, keyP, keyR, row_start, cnt, eidx,
                                   cw, cb, w1, bb1, w2, bb2, out);
}